// Round 23
// baseline (305.545 us; speedup 1.0000x reference)
//
#include <hip/hip_runtime.h>
#include <hip/hip_bf16.h>
#include <math.h>

#define NF 1433
#define NH 16
#define NC 7
#define NCH 45          // ceil(1433/32) 32-col K-chunks (Wb layout)
#define NBKT_MAX 1024   // bucket = dst>>7 -> supports n <= 131072
#define SC_C 3072       // edges per bscatter block (LDS-sortable chunk)
#define CAP 4608        // fixed bucket capacity (mean 4096, sigma ~64 -> 8 sigma)
#define SMASK 0x1FFFFFFu  // low 25 bits = src; high 7 bits = dst&127

typedef __attribute__((ext_vector_type(8))) short bf16x8;
typedef __attribute__((ext_vector_type(4))) float f32x4;

__device__ __forceinline__ unsigned short f2bf(float f) {
  unsigned int u = __float_as_uint(f);
  unsigned int r = (u + 0x7FFFu + ((u >> 16) & 1u)) >> 16;  // RNE
  return (unsigned short)r;
}
__device__ __forceinline__ short f2bfs(float f) {
  union { __hip_bfloat16 h; short s; } u;
  u.h = __float2bfloat16(f);
  return u.s;
}
__device__ __forceinline__ unsigned int packbf(float lo, float hi) {
  return (unsigned int)f2bf(lo) | ((unsigned int)f2bf(hi) << 16);
}
// a[i] += 8 bf16 (packed uint4)
__device__ __forceinline__ void acc8(float* a, uint4 r) {
  a[0] += __uint_as_float(r.x << 16); a[1] += __uint_as_float(r.x & 0xffff0000u);
  a[2] += __uint_as_float(r.y << 16); a[3] += __uint_as_float(r.y & 0xffff0000u);
  a[4] += __uint_as_float(r.z << 16); a[5] += __uint_as_float(r.z & 0xffff0000u);
  a[6] += __uint_as_float(r.w << 16); a[7] += __uint_as_float(r.w & 0xffff0000u);
}
// a[i] += c * bf16[i]  (for unscaled hs1 gathers)
__device__ __forceinline__ void acc8f(float* a, uint4 r, float c) {
  a[0] = fmaf(__uint_as_float(r.x << 16), c, a[0]);
  a[1] = fmaf(__uint_as_float(r.x & 0xffff0000u), c, a[1]);
  a[2] = fmaf(__uint_as_float(r.y << 16), c, a[2]);
  a[3] = fmaf(__uint_as_float(r.y & 0xffff0000u), c, a[3]);
  a[4] = fmaf(__uint_as_float(r.z << 16), c, a[4]);
  a[5] = fmaf(__uint_as_float(r.z & 0xffff0000u), c, a[5]);
  a[6] = fmaf(__uint_as_float(r.w << 16), c, a[6]);
  a[7] = fmaf(__uint_as_float(r.w & 0xffff0000u), c, a[7]);
}

// async global->LDS DMA, 4B/lane (m104/m108 contract)
#define GLOAD(gp, lp) __builtin_amdgcn_global_load_lds(                     \
    (const __attribute__((address_space(1))) void*)(gp),                    \
    (__attribute__((address_space(3))) void*)(lp), 4, 0, 0)

// ---------------- prep: pack W1 fragments + init bucket cursors ----------
__global__ void k_prep(const float* __restrict__ W1, short* __restrict__ Wb,
                       int* __restrict__ bfill) {
  int t = blockIdx.x * blockDim.x + threadIdx.x;
  if (t < NBKT_MAX) bfill[t * 16] = t * CAP;   // fixed-cap bucket bases
  if (t >= NCH * 64 * 8) return;
  int i = t & 7, l = (t >> 3) & 63, c = t >> 9;
  int g = l >> 4, col = l & 15;
  int k = c * 32 + g * 8 + i;
  float v = (k < NF) ? W1[(size_t)k * NH + col] : 0.f;
  Wb[t] = (short)f2bf(v);
}

// ---------------- fused: bscatter (blk%7==0) || GEMM1 (rest), interleaved --
__global__ __launch_bounds__(256) void k_fused(
    const float* __restrict__ x, const short* __restrict__ Wb,
    const int* __restrict__ ei, int* __restrict__ bfill,
    int* __restrict__ ebuf, unsigned short* __restrict__ hs1,
    int n, int E, int nbkt, int nsb) {
  __shared__ __align__(16) char smem[49664];
  int blk = blockIdx.x, t = threadIdx.x;
  int q = blk / 7, r7 = blk % 7;
  bool is_scatter = (r7 == 0) && (q < nsb);

  if (is_scatter) {
    // ================= bscatter path =================
    int* h   = (int*)smem;                       // [1024] hist, then cursor
    int* lo  = h + NBKT_MAX;                     // [1024] block-local base
    int* lb  = lo + NBKT_MAX;                    // [1024] reserved global base
    int* wtot = lb + NBKT_MAX;                   // [8] wave totals
    int* sval = wtot + 8;                        // [3072]
    unsigned short* sbkt = (unsigned short*)(sval + SC_C);  // [3072]
    const int* src = ei;
    const int* dst = ei + E;
    for (int i = t; i < NBKT_MAX; i += 256) h[i] = 0;
    __syncthreads();
    int e0 = q * SC_C;
    int e1 = min(E, e0 + SC_C);
    int csize = e1 - e0;
    for (int e = e0 + t; e < e1; e += 256)
      atomicAdd(&h[((unsigned)dst[e]) >> 7], 1);
    __syncthreads();
    // 1024-entry exclusive scan via 4-wave shfl (2 barriers, not 64)
    {
      int lane = t & 63, wvq = t >> 6;
      int v0 = h[4 * t], v1 = h[4 * t + 1], v2 = h[4 * t + 2], v3 = h[4 * t + 3];
      int s4 = v0 + v1 + v2 + v3;
      int inc = s4;
#pragma unroll
      for (int o = 1; o < 64; o <<= 1) {
        int u = __shfl_up(inc, o, 64);
        if (lane >= o) inc += u;
      }
      if (lane == 63) wtot[wvq] = inc;
      __syncthreads();
      int wbase = 0;
#pragma unroll
      for (int wq = 0; wq < 4; ++wq) wbase += (wq < wvq) ? wtot[wq] : 0;
      int base = wbase + inc - s4;
      lo[4 * t]     = base;
      lo[4 * t + 1] = base + v0;
      lo[4 * t + 2] = base + v0 + v1;
      lo[4 * t + 3] = base + v0 + v1 + v2;
    }
    __syncthreads();
    for (int i = t; i < nbkt; i += 256) {       // reserve global ranges
      int c = h[i];
      lb[i] = c ? atomicAdd(&bfill[i * 16], c) : 0;
      h[i] = 0;
    }
    __syncthreads();
    for (int e = e0 + t; e < e1; e += 256) {    // sort chunk into LDS
      unsigned d = (unsigned)dst[e];
      int bk = d >> 7;
      int p = lo[bk] + atomicAdd(&h[bk], 1);
      sval[p] = (int)(((d & 127u) << 25) | (unsigned)src[e]);
      sbkt[p] = (unsigned short)bk;
    }
    __syncthreads();
    for (int i = t; i < csize; i += 256) {      // coalesced run writes
      int bk = sbkt[i];
      ebuf[lb[bk] + (i - lo[bk])] = sval[i];
    }
    return;
  }

  // ================= GEMM path (r14 pipeline, unscaled output) =============
  int gemm_id = blk - min((blk + 6) / 7, nsb);
  float* xsf = (float*)smem;
#define XIDX(B, ROW, COL) ((((B) * 16 + (ROW)) * 388) + (COL))
  int l = t & 63, wv = t >> 6;
  int row0 = gemm_id << 4;
  int rl = l & 15, g = l >> 4;

  const bf16x8* wp = (const bf16x8*)Wb + l;
  f32x4 acc;
#pragma unroll
  for (int j = 0; j < 4; ++j) acc[j] = 0.f;

  const float* rp[4];
#pragma unroll
  for (int r = 0; r < 4; ++r) {
    int row = row0 + 4 * wv + r;
    rp[r] = x + (size_t)((row < n) ? row : (n - 1)) * NF;
  }

#define STAGE6(M0, B) do {                                                   \
    _Pragma("unroll") for (int r = 0; r < 4; ++r)                            \
    _Pragma("unroll") for (int j = 0; j < 6; ++j)                            \
      GLOAD(rp[r] + (M0) + j * 64 + l, xsf + XIDX(B, 4 * wv + r, j * 64));   \
  } while (0)

#define DOCHUNK(B, CC, WREG) do {                                            \
    const float4* p = (const float4*)(xsf + XIDX(B, rl, (CC) * 32 + g * 8)); \
    float4 a0 = p[0], a1 = p[1];                                             \
    bf16x8 af;                                                               \
    af[0] = f2bfs(a0.x); af[1] = f2bfs(a0.y);                                \
    af[2] = f2bfs(a0.z); af[3] = f2bfs(a0.w);                                \
    af[4] = f2bfs(a1.x); af[5] = f2bfs(a1.y);                                \
    af[6] = f2bfs(a1.z); af[7] = f2bfs(a1.w);                                \
    acc = __builtin_amdgcn_mfma_f32_16x16x32_bf16(af, WREG, acc, 0, 0, 0);   \
  } while (0)

  STAGE6(0, 0);
  bf16x8 w0 = wp[(size_t)(wv) * 64];
  bf16x8 w1 = wp[(size_t)(wv + 4) * 64];
  bf16x8 w2 = wp[(size_t)(wv + 8) * 64];
  STAGE6(384, 1);
  asm volatile("s_waitcnt vmcnt(24) lgkmcnt(0)" ::: "memory");
  __builtin_amdgcn_s_barrier();
  DOCHUNK(0, wv, w0); DOCHUNK(0, wv + 4, w1); DOCHUNK(0, wv + 8, w2);
  __builtin_amdgcn_s_barrier();
  w0 = wp[(size_t)(12 + wv) * 64];
  w1 = wp[(size_t)(16 + wv) * 64];
  w2 = wp[(size_t)(20 + wv) * 64];
  STAGE6(768, 0);
  asm volatile("s_waitcnt vmcnt(24) lgkmcnt(0)" ::: "memory");
  __builtin_amdgcn_s_barrier();
  DOCHUNK(1, wv, w0); DOCHUNK(1, wv + 4, w1); DOCHUNK(1, wv + 8, w2);
  __builtin_amdgcn_s_barrier();
  w0 = wp[(size_t)(24 + wv) * 64];
  w1 = wp[(size_t)(28 + wv) * 64];
  w2 = wp[(size_t)(32 + wv) * 64];
#pragma unroll
  for (int r = 0; r < 4; ++r) {
#pragma unroll
    for (int j = 0; j < 4; ++j)
      GLOAD(rp[r] + 1152 + j * 64 + l, xsf + XIDX(1, 4 * wv + r, j * 64));
    GLOAD(rp[r] + (NF - 64) + l, xsf + XIDX(1, 4 * wv + r, 217));
  }
  if (l < 28) xsf[XIDX(1, 4 * wv + (l / 7), 281 + (l % 7))] = 0.f;
  asm volatile("s_waitcnt vmcnt(20) lgkmcnt(0)" ::: "memory");
  __builtin_amdgcn_s_barrier();
  DOCHUNK(0, wv, w0); DOCHUNK(0, wv + 4, w1); DOCHUNK(0, wv + 8, w2);
  __builtin_amdgcn_s_barrier();
  w0 = wp[(size_t)(36 + wv) * 64];
  w1 = wp[(size_t)(40 + wv) * 64];
  bf16x8 w2b = wp[(size_t)44 * 64];
  asm volatile("s_waitcnt vmcnt(0) lgkmcnt(0)" ::: "memory");
  __builtin_amdgcn_s_barrier();
  DOCHUNK(1, wv, w0); DOCHUNK(1, wv + 4, w1);
  if (wv == 0) DOCHUNK(1, 8, w2b);
  __syncthreads();

  float* ps = xsf;
#pragma unroll
  for (int r = 0; r < 4; ++r)
    ps[(wv * 16 + g * 4 + r) * 16 + rl] = acc[r];
  __syncthreads();
  if (wv == 0) {
    int row = l >> 2, c0 = (l & 3) * 4;
    float4 s0 = *(const float4*)&ps[(row) * 16 + c0];
    float4 s1 = *(const float4*)&ps[(16 + row) * 16 + c0];
    float4 s2 = *(const float4*)&ps[(32 + row) * 16 + c0];
    float4 s3 = *(const float4*)&ps[(48 + row) * 16 + c0];
    int grow = row0 + row;
    if (grow < n) {
      ushort4 o;
      o.x = f2bf(s0.x + s1.x + s2.x + s3.x);
      o.y = f2bf(s0.y + s1.y + s2.y + s3.y);
      o.z = f2bf(s0.z + s1.z + s2.z + s3.z);
      o.w = f2bf(s0.w + s1.w + s2.w + s3.w);
      *(ushort4*)(hs1 + (size_t)grow * NH + c0) = o;
    }
  }
#undef STAGE6
#undef DOCHUNK
#undef XIDX
}

// ---------------- bcsr: LDS-staged per-bucket CSR (782 blocks, 128 nodes) --
__global__ __launch_bounds__(256) void k_bcsr(const int* __restrict__ ebuf,
                                              const int* __restrict__ bfill,
                                              int* __restrict__ off,
                                              int* __restrict__ end,
                                              int* __restrict__ srcs,
                                              float* __restrict__ dis, int n) {
  __shared__ int s_in[CAP];    // 18 KB
  __shared__ int s_out[CAP];   // 18 KB
  __shared__ int s_cnt[256];
  __shared__ int s_sc[256];
  int b = blockIdx.x, t = threadIdx.x;
  int eb = b * CAP;
  int cnt = bfill[b * 16] - eb;
  int cnt4 = cnt >> 2;

  const int4* e4 = (const int4*)(ebuf + eb);
  for (int i = t; i < cnt4; i += 256) ((int4*)s_in)[i] = e4[i];
  for (int i = cnt4 * 4 + t; i < cnt; i += 256) s_in[i] = ebuf[eb + i];
  s_cnt[t] = 0;
  __syncthreads();
  for (int i = t; i < cnt; i += 256)
    atomicAdd(&s_cnt[((unsigned)s_in[i]) >> 25], 1);
  __syncthreads();
  int deg = s_cnt[t];
  s_sc[t] = deg;
  __syncthreads();
  for (int o = 1; o < 256; o <<= 1) {
    int u = (t >= o) ? s_sc[t - o] : 0;
    __syncthreads();
    s_sc[t] += u;
    __syncthreads();
  }
  int excl = s_sc[t] - deg;
  int node = (b << 7) + t;
  if (t < 128 && node < n) {
    off[node] = eb + excl;
    end[node] = eb + excl + deg;
    dis[node] = rsqrtf((float)deg + 1.0f);
  }
  __syncthreads();
  s_cnt[t] = excl;
  __syncthreads();
  for (int i = t; i < cnt; i += 256) {
    unsigned v = (unsigned)s_in[i];
    int slot = atomicAdd(&s_cnt[v >> 25], 1);
    s_out[slot] = (int)(v & SMASK);
  }
  __syncthreads();
  int4* sr4 = (int4*)(srcs + eb);
  for (int i = t; i < cnt4; i += 256) sr4[i] = ((int4*)s_out)[i];
  for (int i = cnt4 * 4 + t; i < cnt; i += 256) srcs[eb + i] = s_out[i];
}

// ---------------- pull1 + bias + relu + GEMM2 fused (16 lanes/node) --------
__global__ __launch_bounds__(256) void k_pull1(
    const int* __restrict__ off, const int* __restrict__ end,
    const int* __restrict__ srcs, const float* __restrict__ dis,
    const uint4* __restrict__ hs1, const float* __restrict__ b1,
    const float* __restrict__ W2, uint4* __restrict__ hs2, int n) {
  int t = blockIdx.x * blockDim.x + threadIdx.x;
  int d = t >> 4;
  if (d >= n) return;
  int sub = t & 15, half = sub & 1, ph = sub >> 1;  // ph in [0,8)
  float dd = dis[d];

  float a[8] = {0.f, 0.f, 0.f, 0.f, 0.f, 0.f, 0.f, 0.f};
  if (ph == 0) acc8f(a, hs1[(size_t)d * 2 + half], dd);  // self loop

  int k = off[d] + ph, k1 = end[d];
  for (; k + 8 < k1; k += 16) {
    int s0 = srcs[k], s1 = srcs[k + 8];
    float c0 = dis[s0], c1 = dis[s1];
    uint4 r0 = hs1[(size_t)s0 * 2 + half];
    uint4 r1 = hs1[(size_t)s1 * 2 + half];
    acc8f(a, r0, c0);
    acc8f(a, r1, c1);
  }
  if (k < k1) {
    int s = srcs[k];
    acc8f(a, hs1[(size_t)s * 2 + half], dis[s]);
  }

#pragma unroll
  for (int i = 0; i < 8; ++i) {
    a[i] += __shfl_xor(a[i], 2);
    a[i] += __shfl_xor(a[i], 4);
    a[i] += __shfl_xor(a[i], 8);
  }

  float v[8];
#pragma unroll
  for (int i = 0; i < 8; ++i) v[i] = fmaxf(a[i] * dd + b1[half * 8 + i], 0.f);
  float p[NC];
#pragma unroll
  for (int c = 0; c < NC; ++c) {
    float s = 0.f;
#pragma unroll
    for (int i = 0; i < 8; ++i) s = fmaf(v[i], W2[(half * 8 + i) * NC + c], s);
    p[c] = s;
  }
#pragma unroll
  for (int c = 0; c < NC; ++c) p[c] += __shfl_xor(p[c], 1);
  if (sub == 0) {
    uint4 o;
    o.x = packbf(p[0] * dd, p[1] * dd);
    o.y = packbf(p[2] * dd, p[3] * dd);
    o.z = packbf(p[4] * dd, p[5] * dd);
    o.w = packbf(p[6] * dd, 0.f);
    hs2[d] = o;
  }
}

// ---------------- pull2 + bias + relu + log_softmax (8 lanes/node) ---------
__global__ __launch_bounds__(256) void k_pull2(
    const int* __restrict__ off, const int* __restrict__ end,
    const int* __restrict__ srcs, const float* __restrict__ dis,
    const uint4* __restrict__ hs2, const float* __restrict__ b2,
    float* __restrict__ out, int n) {
  int t = blockIdx.x * blockDim.x + threadIdx.x;
  int d = t >> 3;
  if (d >= n) return;
  int ph = t & 7;

  float a[8] = {0.f, 0.f, 0.f, 0.f, 0.f, 0.f, 0.f, 0.f};
  if (ph == 0) acc8(a, hs2[d]);  // self loop (hs2 pre-scaled)

  int k = off[d] + ph, k1 = end[d];
  for (; k + 8 < k1; k += 16) {
    int s0 = srcs[k], s1 = srcs[k + 8];
    uint4 r0 = hs2[s0];
    uint4 r1 = hs2[s1];
    acc8(a, r0);
    acc8(a, r1);
  }
  if (k < k1) acc8(a, hs2[srcs[k]]);

#pragma unroll
  for (int i = 0; i < 8; ++i) {
    a[i] += __shfl_xor(a[i], 1);
    a[i] += __shfl_xor(a[i], 2);
    a[i] += __shfl_xor(a[i], 4);
  }
  float dd = dis[d];
  float u[NC];
#pragma unroll
  for (int c = 0; c < NC; ++c) u[c] = fmaxf(a[c] * dd + b2[c], 0.f);
  float m = u[0];
#pragma unroll
  for (int c = 1; c < NC; ++c) m = fmaxf(m, u[c]);
  float sum = 0.f;
#pragma unroll
  for (int c = 0; c < NC; ++c) sum += expf(u[c] - m);
  float lg = logf(sum);
  if (ph < NC) out[(size_t)d * NC + ph] = u[ph] - m - lg;
}

extern "C" void kernel_launch(void* const* d_in, const int* in_sizes, int n_in,
                              void* d_out, int out_size, void* d_ws, size_t ws_size,
                              hipStream_t stream) {
  const float* x  = (const float*)d_in[0];
  const int*   ei = (const int*)d_in[1];
  const float* W1 = (const float*)d_in[2];
  const float* b1 = (const float*)d_in[3];
  const float* W2 = (const float*)d_in[4];
  const float* b2 = (const float*)d_in[5];
  int n = in_sizes[0] / NF;   // 100000
  int E = in_sizes[1] / 2;    // 3200000
  int nbkt = (n + 127) >> 7;  // 782

  // workspace layout (each region 16B-aligned)
  char* w = (char*)d_ws;
#define TAKE(ptrty, name, bytes) \
  ptrty name = (ptrty)w; w += ((size_t)(bytes) + 15) & ~(size_t)15;
  TAKE(unsigned short*, hs1,  sizeof(short) * (size_t)n * NH)
  TAKE(uint4*,          hs2,  16 * (size_t)n)
  TAKE(float*,          dis,  sizeof(float) * n)
  TAKE(short*,          Wb,   sizeof(short) * NCH * 64 * 8)
  TAKE(int*,            bfill,sizeof(int) * 16 * NBKT_MAX)
  TAKE(int*,            ebuf, sizeof(int) * (size_t)NBKT_MAX * CAP)
  TAKE(int*,            off,  sizeof(int) * n)
  TAKE(int*,            end,  sizeof(int) * n)
  TAKE(int*,            srcs, sizeof(int) * (size_t)NBKT_MAX * CAP)
#undef TAKE
  float* out = (float*)d_out;

  int nsb = (E + SC_C - 1) / SC_C;  // 1042
  int ntb = (n + 15) / 16;          // 6250 gemm tiles

  // prep: pack W fragments + init fixed-cap bucket cursors
  k_prep<<<(NCH * 64 * 8 + 255) / 256, 256, 0, stream>>>(W1, Wb, bfill);

  // fused, role-interleaved: scatter iff blk%7==0 (1042 scatter + 6250 gemm)
  k_fused<<<nsb + ntb, 256, 0, stream>>>(x, Wb, ei, bfill, ebuf, hs1,
                                         n, E, nbkt, nsb);

  // PROBE: back-end kernels launched TWICE each (all idempotent).
  // B = bcsr + pull1 + pull2 = T23 - 236.3; next round drops the dupes.
  k_bcsr<<<nbkt, 256, 0, stream>>>(ebuf, bfill, off, end, srcs, dis, n);
  k_bcsr<<<nbkt, 256, 0, stream>>>(ebuf, bfill, off, end, srcs, dis, n);
  k_pull1<<<((size_t)n * 16 + 255) / 256, 256, 0, stream>>>(
      off, end, srcs, dis, (const uint4*)hs1, b1, W2, hs2, n);
  k_pull1<<<((size_t)n * 16 + 255) / 256, 256, 0, stream>>>(
      off, end, srcs, dis, (const uint4*)hs1, b1, W2, hs2, n);
  k_pull2<<<((size_t)n * 8 + 255) / 256, 256, 0, stream>>>(
      off, end, srcs, dis, hs2, b2, out, n);
  k_pull2<<<((size_t)n * 8 + 255) / 256, 256, 0, stream>>>(
      off, end, srcs, dis, hs2, b2, out, n);
}

// Round 24
// 219.218 us; speedup vs baseline: 1.3938x; 1.3938x over previous
//
#include <hip/hip_runtime.h>
#include <hip/hip_bf16.h>
#include <math.h>

#define NF 1433
#define NH 16
#define NC 7
#define NCH 45          // ceil(1433/32) 32-col K-chunks (Wb layout)
#define NBKT_MAX 1024   // bucket = dst>>7 -> supports n <= 131072
#define SC_C 3072       // edges per bscatter block (LDS-sortable chunk)
#define CAP 4608        // fixed bucket capacity (mean 4096, sigma ~64 -> 8 sigma)
#define SMASK 0x1FFFFFFu  // low 25 bits = src; high 7 bits = dst&127

typedef __attribute__((ext_vector_type(8))) short bf16x8;
typedef __attribute__((ext_vector_type(4))) float f32x4;

__device__ __forceinline__ unsigned short f2bf(float f) {
  unsigned int u = __float_as_uint(f);
  unsigned int r = (u + 0x7FFFu + ((u >> 16) & 1u)) >> 16;  // RNE
  return (unsigned short)r;
}
__device__ __forceinline__ short f2bfs(float f) {
  union { __hip_bfloat16 h; short s; } u;
  u.h = __float2bfloat16(f);
  return u.s;
}
__device__ __forceinline__ unsigned int packbf(float lo, float hi) {
  return (unsigned int)f2bf(lo) | ((unsigned int)f2bf(hi) << 16);
}
// a[i] += 8 bf16 (packed uint4)
__device__ __forceinline__ void acc8(float* a, uint4 r) {
  a[0] += __uint_as_float(r.x << 16); a[1] += __uint_as_float(r.x & 0xffff0000u);
  a[2] += __uint_as_float(r.y << 16); a[3] += __uint_as_float(r.y & 0xffff0000u);
  a[4] += __uint_as_float(r.z << 16); a[5] += __uint_as_float(r.z & 0xffff0000u);
  a[6] += __uint_as_float(r.w << 16); a[7] += __uint_as_float(r.w & 0xffff0000u);
}

// async global->LDS DMA, 4B/lane (m104/m108 contract)
#define GLOAD(gp, lp) __builtin_amdgcn_global_load_lds(                     \
    (const __attribute__((address_space(1))) void*)(gp),                    \
    (__attribute__((address_space(3))) void*)(lp), 4, 0, 0)

// order fence: keep W preloads / stage issues in program order
#define SEP() asm volatile("" ::: "memory")

// ---------------- prep: pack W1 fragments + init bucket cursors ----------
__global__ void k_prep(const float* __restrict__ W1, short* __restrict__ Wb,
                       int* __restrict__ bfill) {
  int t = blockIdx.x * blockDim.x + threadIdx.x;
  if (t < NBKT_MAX) bfill[t * 16] = t * CAP;   // fixed-cap bucket bases
  if (t >= NCH * 64 * 8) return;
  int i = t & 7, l = (t >> 3) & 63, c = t >> 9;
  int g = l >> 4, col = l & 15;
  int k = c * 32 + g * 8 + i;
  float v = (k < NF) ? W1[(size_t)k * NH + col] : 0.f;
  Wb[t] = (short)f2bf(v);
}

// ---------------- fused: bscatter (blk%7==0) || GEMM1 (rest), interleaved --
// LDS shrunk to 33.3KB (6-mega gemm schedule, stride 260) -> 4 blocks/CU:
// a CU hosts 3 gemm + 1 scatter instead of 2 + 1, cutting the scatter
// displacement of the BW-bound gemm stream. Wait-free (r21 lesson).
__global__ __launch_bounds__(256) void k_fused(
    const float* __restrict__ x, const short* __restrict__ Wb,
    const int* __restrict__ ei, int* __restrict__ bfill,
    int* __restrict__ ebuf, unsigned short* __restrict__ hs1,
    int n, int E, int nbkt, int nsb) {
  __shared__ __align__(16) char smem[33280];   // gemm 33280B, scatter 30752B
  int blk = blockIdx.x, t = threadIdx.x;
  int q = blk / 7, r7 = blk % 7;
  bool is_scatter = (r7 == 0) && (q < nsb);

  if (is_scatter) {
    // ================= bscatter path =================
    int* h   = (int*)smem;                       // [1024] hist, then cursor
    int* lo  = h + NBKT_MAX;                     // [1024] block-local base
    int* lb  = lo + NBKT_MAX;                    // [1024] reserved global base
    int* wtot = lb + NBKT_MAX;                   // [8] wave totals
    int* sval = wtot + 8;                        // [3072]
    unsigned short* sbkt = (unsigned short*)(sval + SC_C);  // [3072]
    const int* src = ei;
    const int* dst = ei + E;
    for (int i = t; i < NBKT_MAX; i += 256) h[i] = 0;
    __syncthreads();
    int e0 = q * SC_C;
    int e1 = min(E, e0 + SC_C);
    int csize = e1 - e0;
    for (int e = e0 + t; e < e1; e += 256)
      atomicAdd(&h[((unsigned)dst[e]) >> 7], 1);
    __syncthreads();
    // 1024-entry exclusive scan via 4-wave shfl (2 barriers)
    {
      int lane = t & 63, wvq = t >> 6;
      int v0 = h[4 * t], v1 = h[4 * t + 1], v2 = h[4 * t + 2], v3 = h[4 * t + 3];
      int s4 = v0 + v1 + v2 + v3;
      int inc = s4;
#pragma unroll
      for (int o = 1; o < 64; o <<= 1) {
        int u = __shfl_up(inc, o, 64);
        if (lane >= o) inc += u;
      }
      if (lane == 63) wtot[wvq] = inc;
      __syncthreads();
      int wbase = 0;
#pragma unroll
      for (int wq = 0; wq < 4; ++wq) wbase += (wq < wvq) ? wtot[wq] : 0;
      int base = wbase + inc - s4;
      lo[4 * t]     = base;
      lo[4 * t + 1] = base + v0;
      lo[4 * t + 2] = base + v0 + v1;
      lo[4 * t + 3] = base + v0 + v1 + v2;
    }
    __syncthreads();
    for (int i = t; i < nbkt; i += 256) {       // reserve global ranges
      int c = h[i];
      lb[i] = c ? atomicAdd(&bfill[i * 16], c) : 0;
      h[i] = 0;
    }
    __syncthreads();
    for (int e = e0 + t; e < e1; e += 256) {    // sort chunk into LDS
      unsigned d = (unsigned)dst[e];
      int bk = d >> 7;
      int p = lo[bk] + atomicAdd(&h[bk], 1);
      sval[p] = (int)(((d & 127u) << 25) | (unsigned)src[e]);
      sbkt[p] = (unsigned short)bk;
    }
    __syncthreads();
    for (int i = t; i < csize; i += 256) {      // coalesced run writes
      int bk = sbkt[i];
      ebuf[lb[bk] + (i - lo[bk])] = sval[i];
    }
    return;
  }

  // ====== GEMM path: 6 megas of 256 cols, W rotated one mega ahead ======
  // (r15 schedule — measured == the 4-mega variant standalone, smaller LDS)
  int gemm_id = blk - min((blk + 6) / 7, nsb);
  float* xsf = (float*)smem;                     // [2][16][260]
#define XI(B, ROW, COL) ((((B) * 16 + (ROW)) * 260) + (COL))
  int l = t & 63, wv = t >> 6;
  int row0 = gemm_id << 4;
  int rl = l & 15, g = l >> 4;

  const bf16x8* wp = (const bf16x8*)Wb + l;
  f32x4 acc;
#pragma unroll
  for (int j = 0; j < 4; ++j) acc[j] = 0.f;

  const float* rp[4];
#pragma unroll
  for (int r = 0; r < 4; ++r) {
    int row = row0 + 4 * wv + r;
    rp[r] = x + (size_t)((row < n) ? row : (n - 1)) * NF;
  }

#define STAGEF(M0, B) do {                                                   \
    _Pragma("unroll") for (int r = 0; r < 4; ++r)                            \
    _Pragma("unroll") for (int j = 0; j < 4; ++j)                            \
      GLOAD(rp[r] + (M0) + j * 64 + l, xsf + XI(B, 4 * wv + r, j * 64));     \
  } while (0)

#define DOCHUNK(B, CC, WREG) do {                                            \
    const float4* p = (const float4*)(xsf + XI(B, rl, (CC) * 32 + g * 8));   \
    float4 a0 = p[0], a1 = p[1];                                             \
    bf16x8 af;                                                               \
    af[0] = f2bfs(a0.x); af[1] = f2bfs(a0.y);                                \
    af[2] = f2bfs(a0.z); af[3] = f2bfs(a0.w);                                \
    af[4] = f2bfs(a1.x); af[5] = f2bfs(a1.y);                                \
    af[6] = f2bfs(a1.z); af[7] = f2bfs(a1.w);                                \
    acc = __builtin_amdgcn_mfma_f32_16x16x32_bf16(af, WREG, acc, 0, 0, 0);   \
  } while (0)

  // prologue: W(0), stage(0), W(1), stage(1)
  bf16x8 w0 = wp[(size_t)(2 * wv) * 64];
  bf16x8 w1 = wp[(size_t)(2 * wv + 1) * 64];
  SEP();
  STAGEF(0, 0);
  SEP();
  bf16x8 wn0 = wp[(size_t)(8 + 2 * wv) * 64];
  bf16x8 wn1 = wp[(size_t)(9 + 2 * wv) * 64];
  SEP();
  STAGEF(256, 1);

  // megas 0..3 (stage m+2 before compute m; W rotated one mega ahead)
#pragma unroll
  for (int m = 0; m < 4; ++m) {
    asm volatile("s_waitcnt vmcnt(18) lgkmcnt(0)" ::: "memory");
    __builtin_amdgcn_s_barrier();
    DOCHUNK(m & 1, 2 * wv, w0);
    DOCHUNK(m & 1, 2 * wv + 1, w1);
    __builtin_amdgcn_s_barrier();
    w0 = wn0; w1 = wn1;
    if (m < 3) {
      wn0 = wp[(size_t)(8 * (m + 2) + 2 * wv) * 64];
      wn1 = wp[(size_t)(8 * (m + 2) + 2 * wv + 1) * 64];
      SEP();
      STAGEF(256 * (m + 2), m & 1);
      SEP();
    } else {
      // W(5): chunk 40+wv (all waves) + chunk 44 (wv0 only); uniform 2/wave
      wn0 = wp[(size_t)(40 + wv) * 64];
      wn1 = wp[(size_t)44 * 64];
      SEP();
      // stage(5) tail -> buf1: cols 1280..1432 = 2 full units + overlap
      // (cols 1369..1432 -> rel 89..152), zero rel 153..159 (chunk-44 pad)
#pragma unroll
      for (int r = 0; r < 4; ++r) {
#pragma unroll
        for (int j = 0; j < 2; ++j)
          GLOAD(rp[r] + 1280 + j * 64 + l, xsf + XI(1, 4 * wv + r, j * 64));
        GLOAD(rp[r] + (NF - 64) + l, xsf + XI(1, 4 * wv + r, 89));
      }
      if (l < 28) xsf[XI(1, 4 * wv + (l / 7), 153 + (l % 7))] = 0.f;
      SEP();
    }
  }

  // mega 4 (buf0, chunks 32+2wv, 33+2wv)
  asm volatile("s_waitcnt vmcnt(14) lgkmcnt(0)" ::: "memory");
  __builtin_amdgcn_s_barrier();
  DOCHUNK(0, 2 * wv, w0);
  DOCHUNK(0, 2 * wv + 1, w1);
  __builtin_amdgcn_s_barrier();
  w0 = wn0; w1 = wn1;

  // mega 5 (tail, buf1: rel chunk wv = global 40+wv; wv0 also rel 4 = 44)
  asm volatile("s_waitcnt vmcnt(0) lgkmcnt(0)" ::: "memory");
  __builtin_amdgcn_s_barrier();
  DOCHUNK(1, wv, w0);
  if (wv == 0) DOCHUNK(1, 4, w1);
  __syncthreads();

  // cross-wave reduce; hs1 stored UNSCALED (bcsr scales it by dis)
  float* ps = xsf;
#pragma unroll
  for (int r = 0; r < 4; ++r)
    ps[(wv * 16 + g * 4 + r) * 16 + rl] = acc[r];
  __syncthreads();
  if (wv == 0) {
    int row = l >> 2, c0 = (l & 3) * 4;
    float4 s0 = *(const float4*)&ps[(row) * 16 + c0];
    float4 s1 = *(const float4*)&ps[(16 + row) * 16 + c0];
    float4 s2 = *(const float4*)&ps[(32 + row) * 16 + c0];
    float4 s3 = *(const float4*)&ps[(48 + row) * 16 + c0];
    int grow = row0 + row;
    if (grow < n) {
      ushort4 o;
      o.x = f2bf(s0.x + s1.x + s2.x + s3.x);
      o.y = f2bf(s0.y + s1.y + s2.y + s3.y);
      o.z = f2bf(s0.z + s1.z + s2.z + s3.z);
      o.w = f2bf(s0.w + s1.w + s2.w + s3.w);
      *(ushort4*)(hs1 + (size_t)grow * NH + c0) = o;
    }
  }
#undef STAGEF
#undef DOCHUNK
#undef XI
}

// ---------------- bcsr: LDS-staged per-bucket CSR + hs1 scaling ------------
// Also scales hs1[node] *= dis[node] in place (moves the per-edge dis
// multiply out of pull1's gather loop).
__global__ __launch_bounds__(256) void k_bcsr(const int* __restrict__ ebuf,
                                              const int* __restrict__ bfill,
                                              int* __restrict__ off,
                                              int* __restrict__ end,
                                              int* __restrict__ srcs,
                                              float* __restrict__ dis,
                                              unsigned short* __restrict__ hs1,
                                              int n) {
  __shared__ int s_in[CAP];    // 18 KB
  __shared__ int s_out[CAP];   // 18 KB
  __shared__ int s_cnt[256];
  __shared__ int s_sc[256];
  __shared__ float s_dis[128];
  int b = blockIdx.x, t = threadIdx.x;
  int eb = b * CAP;
  int cnt = bfill[b * 16] - eb;
  int cnt4 = cnt >> 2;

  const int4* e4 = (const int4*)(ebuf + eb);
  for (int i = t; i < cnt4; i += 256) ((int4*)s_in)[i] = e4[i];
  for (int i = cnt4 * 4 + t; i < cnt; i += 256) s_in[i] = ebuf[eb + i];
  s_cnt[t] = 0;
  __syncthreads();
  for (int i = t; i < cnt; i += 256)
    atomicAdd(&s_cnt[((unsigned)s_in[i]) >> 25], 1);
  __syncthreads();
  int deg = s_cnt[t];
  s_sc[t] = deg;
  __syncthreads();
  for (int o = 1; o < 256; o <<= 1) {
    int u = (t >= o) ? s_sc[t - o] : 0;
    __syncthreads();
    s_sc[t] += u;
    __syncthreads();
  }
  int excl = s_sc[t] - deg;
  int node = (b << 7) + t;
  if (t < 128 && node < n) {
    float dd = rsqrtf((float)deg + 1.0f);
    off[node] = eb + excl;
    end[node] = eb + excl + deg;
    dis[node] = dd;
    s_dis[t] = dd;
  }
  __syncthreads();
  s_cnt[t] = excl;
  __syncthreads();
  for (int i = t; i < cnt; i += 256) {
    unsigned v = (unsigned)s_in[i];
    int slot = atomicAdd(&s_cnt[v >> 25], 1);
    s_out[slot] = (int)(v & SMASK);
  }
  __syncthreads();
  int4* sr4 = (int4*)(srcs + eb);
  for (int i = t; i < cnt4; i += 256) sr4[i] = ((int4*)s_out)[i];
  for (int i = cnt4 * 4 + t; i < cnt; i += 256) srcs[eb + i] = s_out[i];

  // scale hs1 rows by dis (256 threads = 128 nodes x 2 halves)
  {
    int nl = t >> 1, hf = t & 1;
    int nd = (b << 7) + nl;
    if (nd < n) {
      float dd = s_dis[nl];
      uint4* hp = (uint4*)hs1 + (size_t)nd * 2 + hf;
      uint4 r = *hp;
      uint4 o;
      o.x = packbf(__uint_as_float(r.x << 16) * dd,
                   __uint_as_float(r.x & 0xffff0000u) * dd);
      o.y = packbf(__uint_as_float(r.y << 16) * dd,
                   __uint_as_float(r.y & 0xffff0000u) * dd);
      o.z = packbf(__uint_as_float(r.z << 16) * dd,
                   __uint_as_float(r.z & 0xffff0000u) * dd);
      o.w = packbf(__uint_as_float(r.w << 16) * dd,
                   __uint_as_float(r.w & 0xffff0000u) * dd);
      *hp = o;
    }
  }
}

// ---------------- pull1 + bias + relu + GEMM2 fused (16 lanes/node) --------
// hs1 pre-scaled by dis[src] (bcsr) -> lean gather loop, no dis loads.
__global__ __launch_bounds__(256) void k_pull1(
    const int* __restrict__ off, const int* __restrict__ end,
    const int* __restrict__ srcs, const float* __restrict__ dis,
    const uint4* __restrict__ hs1, const float* __restrict__ b1,
    const float* __restrict__ W2, uint4* __restrict__ hs2, int n) {
  int t = blockIdx.x * blockDim.x + threadIdx.x;
  int d = t >> 4;
  if (d >= n) return;
  int sub = t & 15, half = sub & 1, ph = sub >> 1;  // ph in [0,8)

  float a[8] = {0.f, 0.f, 0.f, 0.f, 0.f, 0.f, 0.f, 0.f};
  if (ph == 0) acc8(a, hs1[(size_t)d * 2 + half]);  // self loop (pre-scaled)

  int k = off[d] + ph, k1 = end[d];
  for (; k + 8 < k1; k += 16) {  // 2 independent gathers in flight
    int s0 = srcs[k], s1 = srcs[k + 8];
    uint4 r0 = hs1[(size_t)s0 * 2 + half];
    uint4 r1 = hs1[(size_t)s1 * 2 + half];
    acc8(a, r0);
    acc8(a, r1);
  }
  if (k < k1) acc8(a, hs1[(size_t)srcs[k] * 2 + half]);

#pragma unroll
  for (int i = 0; i < 8; ++i) {  // reduce over the 8 phases (lane bits 1..3)
    a[i] += __shfl_xor(a[i], 2);
    a[i] += __shfl_xor(a[i], 4);
    a[i] += __shfl_xor(a[i], 8);
  }

  float dd = dis[d];
  float v[8];
#pragma unroll
  for (int i = 0; i < 8; ++i) v[i] = fmaxf(a[i] * dd + b1[half * 8 + i], 0.f);
  float p[NC];
#pragma unroll
  for (int c = 0; c < NC; ++c) {
    float s = 0.f;
#pragma unroll
    for (int i = 0; i < 8; ++i) s = fmaf(v[i], W2[(half * 8 + i) * NC + c], s);
    p[c] = s;
  }
#pragma unroll
  for (int c = 0; c < NC; ++c) p[c] += __shfl_xor(p[c], 1);  // combine halves
  if (sub == 0) {
    uint4 o;
    o.x = packbf(p[0] * dd, p[1] * dd);
    o.y = packbf(p[2] * dd, p[3] * dd);
    o.z = packbf(p[4] * dd, p[5] * dd);
    o.w = packbf(p[6] * dd, 0.f);  // pad col
    hs2[d] = o;
  }
}

// ---------------- pull2 + bias + relu + log_softmax (8 lanes/node) ---------
__global__ __launch_bounds__(256) void k_pull2(
    const int* __restrict__ off, const int* __restrict__ end,
    const int* __restrict__ srcs, const float* __restrict__ dis,
    const uint4* __restrict__ hs2, const float* __restrict__ b2,
    float* __restrict__ out, int n) {
  int t = blockIdx.x * blockDim.x + threadIdx.x;
  int d = t >> 3;
  if (d >= n) return;
  int ph = t & 7;

  float a[8] = {0.f, 0.f, 0.f, 0.f, 0.f, 0.f, 0.f, 0.f};
  if (ph == 0) acc8(a, hs2[d]);  // self loop (hs2 pre-scaled)

  int k = off[d] + ph, k1 = end[d];
  for (; k + 8 < k1; k += 16) {
    int s0 = srcs[k], s1 = srcs[k + 8];
    uint4 r0 = hs2[s0];
    uint4 r1 = hs2[s1];
    acc8(a, r0);
    acc8(a, r1);
  }
  if (k < k1) acc8(a, hs2[srcs[k]]);

#pragma unroll
  for (int i = 0; i < 8; ++i) {
    a[i] += __shfl_xor(a[i], 1);
    a[i] += __shfl_xor(a[i], 2);
    a[i] += __shfl_xor(a[i], 4);
  }
  float dd = dis[d];
  float u[NC];
#pragma unroll
  for (int c = 0; c < NC; ++c) u[c] = fmaxf(a[c] * dd + b2[c], 0.f);
  float m = u[0];
#pragma unroll
  for (int c = 1; c < NC; ++c) m = fmaxf(m, u[c]);
  float sum = 0.f;
#pragma unroll
  for (int c = 0; c < NC; ++c) sum += expf(u[c] - m);
  float lg = logf(sum);
  if (ph < NC) out[(size_t)d * NC + ph] = u[ph] - m - lg;
}

extern "C" void kernel_launch(void* const* d_in, const int* in_sizes, int n_in,
                              void* d_out, int out_size, void* d_ws, size_t ws_size,
                              hipStream_t stream) {
  const float* x  = (const float*)d_in[0];
  const int*   ei = (const int*)d_in[1];
  const float* W1 = (const float*)d_in[2];
  const float* b1 = (const float*)d_in[3];
  const float* W2 = (const float*)d_in[4];
  const float* b2 = (const float*)d_in[5];
  int n = in_sizes[0] / NF;   // 100000
  int E = in_sizes[1] / 2;    // 3200000
  int nbkt = (n + 127) >> 7;  // 782

  // workspace layout (each region 16B-aligned)
  char* w = (char*)d_ws;
#define TAKE(ptrty, name, bytes) \
  ptrty name = (ptrty)w; w += ((size_t)(bytes) + 15) & ~(size_t)15;
  TAKE(unsigned short*, hs1,  sizeof(short) * (size_t)n * NH)
  TAKE(uint4*,          hs2,  16 * (size_t)n)
  TAKE(float*,          dis,  sizeof(float) * n)
  TAKE(short*,          Wb,   sizeof(short) * NCH * 64 * 8)
  TAKE(int*,            bfill,sizeof(int) * 16 * NBKT_MAX)
  TAKE(int*,            ebuf, sizeof(int) * (size_t)NBKT_MAX * CAP)
  TAKE(int*,            off,  sizeof(int) * n)
  TAKE(int*,            end,  sizeof(int) * n)
  TAKE(int*,            srcs, sizeof(int) * (size_t)NBKT_MAX * CAP)
#undef TAKE
  float* out = (float*)d_out;

  int nsb = (E + SC_C - 1) / SC_C;  // 1042
  int ntb = (n + 15) / 16;          // 6250 gemm tiles

  // prep: pack W fragments + init fixed-cap bucket cursors
  k_prep<<<(NCH * 64 * 8 + 255) / 256, 256, 0, stream>>>(W1, Wb, bfill);

  // fused, role-interleaved: scatter iff blk%7==0 (1042 scatter + 6250 gemm)
  k_fused<<<nsb + ntb, 256, 0, stream>>>(x, Wb, ei, bfill, ebuf, hs1,
                                         n, E, nbkt, nsb);

  k_bcsr<<<nbkt, 256, 0, stream>>>(ebuf, bfill, off, end, srcs, dis, hs1, n);
  k_pull1<<<((size_t)n * 16 + 255) / 256, 256, 0, stream>>>(
      off, end, srcs, dis, (const uint4*)hs1, b1, W2, hs2, n);
  k_pull2<<<((size_t)n * 8 + 255) / 256, 256, 0, stream>>>(
      off, end, srcs, dis, hs2, b2, out, n);
}

// Round 25
// 218.913 us; speedup vs baseline: 1.3957x; 1.0014x over previous
//
#include <hip/hip_runtime.h>
#include <hip/hip_bf16.h>
#include <math.h>

#define NF 1433
#define NH 16
#define NC 7
#define NCH 45          // ceil(1433/32) 32-col K-chunks (Wb layout)
#define NBKT_MAX 1024   // bucket = dst>>7 -> supports n <= 131072
#define SC_C 3072       // edges per bscatter block (LDS-sortable chunk)
#define CAP 4608        // fixed bucket capacity (mean 4096, sigma ~64 -> 8 sigma)
#define SMASK 0x1FFFFFFu  // low 25 bits = src; high 7 bits = dst&127

typedef __attribute__((ext_vector_type(8))) short bf16x8;
typedef __attribute__((ext_vector_type(4))) float f32x4;

__device__ __forceinline__ unsigned short f2bf(float f) {
  unsigned int u = __float_as_uint(f);
  unsigned int r = (u + 0x7FFFu + ((u >> 16) & 1u)) >> 16;  // RNE
  return (unsigned short)r;
}
__device__ __forceinline__ short f2bfs(float f) {
  union { __hip_bfloat16 h; short s; } u;
  u.h = __float2bfloat16(f);
  return u.s;
}
__device__ __forceinline__ unsigned int packbf(float lo, float hi) {
  return (unsigned int)f2bf(lo) | ((unsigned int)f2bf(hi) << 16);
}
// a[i] += 8 bf16 (packed uint4)
__device__ __forceinline__ void acc8(float* a, uint4 r) {
  a[0] += __uint_as_float(r.x << 16); a[1] += __uint_as_float(r.x & 0xffff0000u);
  a[2] += __uint_as_float(r.y << 16); a[3] += __uint_as_float(r.y & 0xffff0000u);
  a[4] += __uint_as_float(r.z << 16); a[5] += __uint_as_float(r.z & 0xffff0000u);
  a[6] += __uint_as_float(r.w << 16); a[7] += __uint_as_float(r.w & 0xffff0000u);
}

// async global->LDS DMA, 4B/lane (m104/m108 contract)
#define GLOAD(gp, lp) __builtin_amdgcn_global_load_lds(                     \
    (const __attribute__((address_space(1))) void*)(gp),                    \
    (__attribute__((address_space(3))) void*)(lp), 4, 0, 0)

// order fence: keep W preloads / stage issues in program order
#define SEP() asm volatile("" ::: "memory")

// ---------------- prep: pack W1 fragments + init bucket cursors ----------
__global__ void k_prep(const float* __restrict__ W1, short* __restrict__ Wb,
                       int* __restrict__ bfill) {
  int t = blockIdx.x * blockDim.x + threadIdx.x;
  if (t < NBKT_MAX) bfill[t * 16] = t * CAP;   // fixed-cap bucket bases
  if (t >= NCH * 64 * 8) return;
  int i = t & 7, l = (t >> 3) & 63, c = t >> 9;
  int g = l >> 4, col = l & 15;
  int k = c * 32 + g * 8 + i;
  float v = (k < NF) ? W1[(size_t)k * NH + col] : 0.f;
  Wb[t] = (short)f2bf(v);
}

// ---------------- fused: bscatter (blk%7==0) || GEMM1 (rest), interleaved --
// 33.3KB LDS -> 4 blocks/CU: CU hosts 3 gemm + 1 scatter. Wait-free.
__global__ __launch_bounds__(256) void k_fused(
    const float* __restrict__ x, const short* __restrict__ Wb,
    const int* __restrict__ ei, int* __restrict__ bfill,
    int* __restrict__ ebuf, unsigned short* __restrict__ hs1,
    int n, int E, int nbkt, int nsb) {
  __shared__ __align__(16) char smem[33280];   // gemm 33280B, scatter 30752B
  int blk = blockIdx.x, t = threadIdx.x;
  int q = blk / 7, r7 = blk % 7;
  bool is_scatter = (r7 == 0) && (q < nsb);

  if (is_scatter) {
    // ================= bscatter path =================
    int* h   = (int*)smem;                       // [1024] hist, then cursor
    int* lo  = h + NBKT_MAX;                     // [1024] block-local base
    int* lb  = lo + NBKT_MAX;                    // [1024] reserved global base
    int* wtot = lb + NBKT_MAX;                   // [8] wave totals
    int* sval = wtot + 8;                        // [3072]
    unsigned short* sbkt = (unsigned short*)(sval + SC_C);  // [3072]
    const int* src = ei;
    const int* dst = ei + E;
    for (int i = t; i < NBKT_MAX; i += 256) h[i] = 0;
    __syncthreads();
    int e0 = q * SC_C;
    int e1 = min(E, e0 + SC_C);
    int csize = e1 - e0;
    for (int e = e0 + t; e < e1; e += 256)
      atomicAdd(&h[((unsigned)dst[e]) >> 7], 1);
    __syncthreads();
    // 1024-entry exclusive scan via 4-wave shfl (2 barriers)
    {
      int lane = t & 63, wvq = t >> 6;
      int v0 = h[4 * t], v1 = h[4 * t + 1], v2 = h[4 * t + 2], v3 = h[4 * t + 3];
      int s4 = v0 + v1 + v2 + v3;
      int inc = s4;
#pragma unroll
      for (int o = 1; o < 64; o <<= 1) {
        int u = __shfl_up(inc, o, 64);
        if (lane >= o) inc += u;
      }
      if (lane == 63) wtot[wvq] = inc;
      __syncthreads();
      int wbase = 0;
#pragma unroll
      for (int wq = 0; wq < 4; ++wq) wbase += (wq < wvq) ? wtot[wq] : 0;
      int base = wbase + inc - s4;
      lo[4 * t]     = base;
      lo[4 * t + 1] = base + v0;
      lo[4 * t + 2] = base + v0 + v1;
      lo[4 * t + 3] = base + v0 + v1 + v2;
    }
    __syncthreads();
    for (int i = t; i < nbkt; i += 256) {       // reserve global ranges
      int c = h[i];
      lb[i] = c ? atomicAdd(&bfill[i * 16], c) : 0;
      h[i] = 0;
    }
    __syncthreads();
    for (int e = e0 + t; e < e1; e += 256) {    // sort chunk into LDS
      unsigned d = (unsigned)dst[e];
      int bk = d >> 7;
      int p = lo[bk] + atomicAdd(&h[bk], 1);
      sval[p] = (int)(((d & 127u) << 25) | (unsigned)src[e]);
      sbkt[p] = (unsigned short)bk;
    }
    __syncthreads();
    for (int i = t; i < csize; i += 256) {      // coalesced run writes
      int bk = sbkt[i];
      ebuf[lb[bk] + (i - lo[bk])] = sval[i];
    }
    return;
  }

  // ====== GEMM path: 6 megas of 256 cols, W rotated one mega ahead ======
  int gemm_id = blk - min((blk + 6) / 7, nsb);
  float* xsf = (float*)smem;                     // [2][16][260]
#define XI(B, ROW, COL) ((((B) * 16 + (ROW)) * 260) + (COL))
  int l = t & 63, wv = t >> 6;
  int row0 = gemm_id << 4;
  int rl = l & 15, g = l >> 4;

  const bf16x8* wp = (const bf16x8*)Wb + l;
  f32x4 acc;
#pragma unroll
  for (int j = 0; j < 4; ++j) acc[j] = 0.f;

  const float* rp[4];
#pragma unroll
  for (int r = 0; r < 4; ++r) {
    int row = row0 + 4 * wv + r;
    rp[r] = x + (size_t)((row < n) ? row : (n - 1)) * NF;
  }

#define STAGEF(M0, B) do {                                                   \
    _Pragma("unroll") for (int r = 0; r < 4; ++r)                            \
    _Pragma("unroll") for (int j = 0; j < 4; ++j)                            \
      GLOAD(rp[r] + (M0) + j * 64 + l, xsf + XI(B, 4 * wv + r, j * 64));     \
  } while (0)

#define DOCHUNK(B, CC, WREG) do {                                            \
    const float4* p = (const float4*)(xsf + XI(B, rl, (CC) * 32 + g * 8));   \
    float4 a0 = p[0], a1 = p[1];                                             \
    bf16x8 af;                                                               \
    af[0] = f2bfs(a0.x); af[1] = f2bfs(a0.y);                                \
    af[2] = f2bfs(a0.z); af[3] = f2bfs(a0.w);                                \
    af[4] = f2bfs(a1.x); af[5] = f2bfs(a1.y);                                \
    af[6] = f2bfs(a1.z); af[7] = f2bfs(a1.w);                                \
    acc = __builtin_amdgcn_mfma_f32_16x16x32_bf16(af, WREG, acc, 0, 0, 0);   \
  } while (0)

  // prologue: W(0), stage(0), W(1), stage(1)
  bf16x8 w0 = wp[(size_t)(2 * wv) * 64];
  bf16x8 w1 = wp[(size_t)(2 * wv + 1) * 64];
  SEP();
  STAGEF(0, 0);
  SEP();
  bf16x8 wn0 = wp[(size_t)(8 + 2 * wv) * 64];
  bf16x8 wn1 = wp[(size_t)(9 + 2 * wv) * 64];
  SEP();
  STAGEF(256, 1);

  // megas 0..3 (stage m+2 before compute m; W rotated one mega ahead)
#pragma unroll
  for (int m = 0; m < 4; ++m) {
    asm volatile("s_waitcnt vmcnt(18) lgkmcnt(0)" ::: "memory");
    __builtin_amdgcn_s_barrier();
    DOCHUNK(m & 1, 2 * wv, w0);
    DOCHUNK(m & 1, 2 * wv + 1, w1);
    __builtin_amdgcn_s_barrier();
    w0 = wn0; w1 = wn1;
    if (m < 3) {
      wn0 = wp[(size_t)(8 * (m + 2) + 2 * wv) * 64];
      wn1 = wp[(size_t)(8 * (m + 2) + 2 * wv + 1) * 64];
      SEP();
      STAGEF(256 * (m + 2), m & 1);
      SEP();
    } else {
      // W(5): chunk 40+wv (all waves) + chunk 44 (wv0 only); uniform 2/wave
      wn0 = wp[(size_t)(40 + wv) * 64];
      wn1 = wp[(size_t)44 * 64];
      SEP();
      // stage(5) tail -> buf1: cols 1280..1432 = 2 full units + overlap
      // (cols 1369..1432 -> rel 89..152), zero rel 153..159 (chunk-44 pad)
#pragma unroll
      for (int r = 0; r < 4; ++r) {
#pragma unroll
        for (int j = 0; j < 2; ++j)
          GLOAD(rp[r] + 1280 + j * 64 + l, xsf + XI(1, 4 * wv + r, j * 64));
        GLOAD(rp[r] + (NF - 64) + l, xsf + XI(1, 4 * wv + r, 89));
      }
      if (l < 28) xsf[XI(1, 4 * wv + (l / 7), 153 + (l % 7))] = 0.f;
      SEP();
    }
  }

  // mega 4 (buf0, chunks 32+2wv, 33+2wv)
  asm volatile("s_waitcnt vmcnt(14) lgkmcnt(0)" ::: "memory");
  __builtin_amdgcn_s_barrier();
  DOCHUNK(0, 2 * wv, w0);
  DOCHUNK(0, 2 * wv + 1, w1);
  __builtin_amdgcn_s_barrier();
  w0 = wn0; w1 = wn1;

  // mega 5 (tail, buf1: rel chunk wv = global 40+wv; wv0 also rel 4 = 44)
  asm volatile("s_waitcnt vmcnt(0) lgkmcnt(0)" ::: "memory");
  __builtin_amdgcn_s_barrier();
  DOCHUNK(1, wv, w0);
  if (wv == 0) DOCHUNK(1, 4, w1);
  __syncthreads();

  // cross-wave reduce; hs1 stored UNSCALED (bcsr scales it by dis)
  float* ps = xsf;
#pragma unroll
  for (int r = 0; r < 4; ++r)
    ps[(wv * 16 + g * 4 + r) * 16 + rl] = acc[r];
  __syncthreads();
  if (wv == 0) {
    int row = l >> 2, c0 = (l & 3) * 4;
    float4 s0 = *(const float4*)&ps[(row) * 16 + c0];
    float4 s1 = *(const float4*)&ps[(16 + row) * 16 + c0];
    float4 s2 = *(const float4*)&ps[(32 + row) * 16 + c0];
    float4 s3 = *(const float4*)&ps[(48 + row) * 16 + c0];
    int grow = row0 + row;
    if (grow < n) {
      ushort4 o;
      o.x = f2bf(s0.x + s1.x + s2.x + s3.x);
      o.y = f2bf(s0.y + s1.y + s2.y + s3.y);
      o.z = f2bf(s0.z + s1.z + s2.z + s3.z);
      o.w = f2bf(s0.w + s1.w + s2.w + s3.w);
      *(ushort4*)(hs1 + (size_t)grow * NH + c0) = o;
    }
  }
#undef STAGEF
#undef DOCHUNK
#undef XI
}

// ---------------- bcsr: LDS-staged per-bucket CSR + hs1 scaling (512 thr) --
// 512 threads halve the serial LDS-atomic rounds (8 vs 16 per pass); LDS
// unchanged (38.5KB -> 4 blocks/CU -> 2048 thr/CU, full occupancy).
__global__ __launch_bounds__(512) void k_bcsr(const int* __restrict__ ebuf,
                                              const int* __restrict__ bfill,
                                              int* __restrict__ off,
                                              int* __restrict__ end,
                                              int* __restrict__ srcs,
                                              float* __restrict__ dis,
                                              unsigned short* __restrict__ hs1,
                                              int n) {
  __shared__ int s_in[CAP];    // 18 KB
  __shared__ int s_out[CAP];   // 18 KB
  __shared__ int s_cnt[256];
  __shared__ int s_sc[256];
  __shared__ float s_dis[128];
  int b = blockIdx.x, t = threadIdx.x;
  int eb = b * CAP;
  int cnt = bfill[b * 16] - eb;
  int cnt4 = cnt >> 2;

  const int4* e4 = (const int4*)(ebuf + eb);
  for (int i = t; i < cnt4; i += 512) ((int4*)s_in)[i] = e4[i];
  for (int i = cnt4 * 4 + t; i < cnt; i += 512) s_in[i] = ebuf[eb + i];
  if (t < 256) s_cnt[t] = 0;
  __syncthreads();
  for (int i = t; i < cnt; i += 512)
    atomicAdd(&s_cnt[((unsigned)s_in[i]) >> 25], 1);
  __syncthreads();
  int deg = (t < 256) ? s_cnt[t] : 0;
  if (t < 256) s_sc[t] = deg;
  __syncthreads();
  for (int o = 1; o < 256; o <<= 1) {
    int u = (t < 256 && t >= o) ? s_sc[t - o] : 0;
    __syncthreads();
    if (t < 256) s_sc[t] += u;
    __syncthreads();
  }
  int excl = (t < 256) ? (s_sc[t] - deg) : 0;
  int node = (b << 7) + t;
  if (t < 128 && node < n) {
    float dd = rsqrtf((float)deg + 1.0f);
    off[node] = eb + excl;
    end[node] = eb + excl + deg;
    dis[node] = dd;
    s_dis[t] = dd;
  }
  __syncthreads();
  if (t < 256) s_cnt[t] = excl;
  __syncthreads();
  for (int i = t; i < cnt; i += 512) {
    unsigned v = (unsigned)s_in[i];
    int slot = atomicAdd(&s_cnt[v >> 25], 1);
    s_out[slot] = (int)(v & SMASK);
  }
  __syncthreads();
  int4* sr4 = (int4*)(srcs + eb);
  for (int i = t; i < cnt4; i += 512) sr4[i] = ((int4*)s_out)[i];
  for (int i = cnt4 * 4 + t; i < cnt; i += 512) srcs[eb + i] = s_out[i];

  // scale hs1 rows by dis (first 256 threads = 128 nodes x 2 halves)
  if (t < 256) {
    int nl = t >> 1, hf = t & 1;
    int nd = (b << 7) + nl;
    if (nd < n) {
      float dd = s_dis[nl];
      uint4* hp = (uint4*)hs1 + (size_t)nd * 2 + hf;
      uint4 r = *hp;
      uint4 o;
      o.x = packbf(__uint_as_float(r.x << 16) * dd,
                   __uint_as_float(r.x & 0xffff0000u) * dd);
      o.y = packbf(__uint_as_float(r.y << 16) * dd,
                   __uint_as_float(r.y & 0xffff0000u) * dd);
      o.z = packbf(__uint_as_float(r.z << 16) * dd,
                   __uint_as_float(r.z & 0xffff0000u) * dd);
      o.w = packbf(__uint_as_float(r.w << 16) * dd,
                   __uint_as_float(r.w & 0xffff0000u) * dd);
      *hp = o;
    }
  }
}

// ---------------- pull1 + bias + relu + GEMM2 fused (16 lanes/node) --------
// hs1 pre-scaled by dis[src] (bcsr) -> lean gather loop, no dis loads.
__global__ __launch_bounds__(256) void k_pull1(
    const int* __restrict__ off, const int* __restrict__ end,
    const int* __restrict__ srcs, const float* __restrict__ dis,
    const uint4* __restrict__ hs1, const float* __restrict__ b1,
    const float* __restrict__ W2, uint4* __restrict__ hs2, int n) {
  int t = blockIdx.x * blockDim.x + threadIdx.x;
  int d = t >> 4;
  if (d >= n) return;
  int sub = t & 15, half = sub & 1, ph = sub >> 1;  // ph in [0,8)

  float a[8] = {0.f, 0.f, 0.f, 0.f, 0.f, 0.f, 0.f, 0.f};
  if (ph == 0) acc8(a, hs1[(size_t)d * 2 + half]);  // self loop (pre-scaled)

  int k = off[d] + ph, k1 = end[d];
  for (; k + 8 < k1; k += 16) {  // 2 independent gathers in flight
    int s0 = srcs[k], s1 = srcs[k + 8];
    uint4 r0 = hs1[(size_t)s0 * 2 + half];
    uint4 r1 = hs1[(size_t)s1 * 2 + half];
    acc8(a, r0);
    acc8(a, r1);
  }
  if (k < k1) acc8(a, hs1[(size_t)srcs[k] * 2 + half]);

#pragma unroll
  for (int i = 0; i < 8; ++i) {  // reduce over the 8 phases (lane bits 1..3)
    a[i] += __shfl_xor(a[i], 2);
    a[i] += __shfl_xor(a[i], 4);
    a[i] += __shfl_xor(a[i], 8);
  }

  float dd = dis[d];
  float v[8];
#pragma unroll
  for (int i = 0; i < 8; ++i) v[i] = fmaxf(a[i] * dd + b1[half * 8 + i], 0.f);
  float p[NC];
#pragma unroll
  for (int c = 0; c < NC; ++c) {
    float s = 0.f;
#pragma unroll
    for (int i = 0; i < 8; ++i) s = fmaf(v[i], W2[(half * 8 + i) * NC + c], s);
    p[c] = s;
  }
#pragma unroll
  for (int c = 0; c < NC; ++c) p[c] += __shfl_xor(p[c], 1);  // combine halves
  if (sub == 0) {
    uint4 o;
    o.x = packbf(p[0] * dd, p[1] * dd);
    o.y = packbf(p[2] * dd, p[3] * dd);
    o.z = packbf(p[4] * dd, p[5] * dd);
    o.w = packbf(p[6] * dd, 0.f);  // pad col
    hs2[d] = o;
  }
}

// ---------------- pull2 + bias + relu + log_softmax (8 lanes/node) ---------
__global__ __launch_bounds__(256) void k_pull2(
    const int* __restrict__ off, const int* __restrict__ end,
    const int* __restrict__ srcs, const float* __restrict__ dis,
    const uint4* __restrict__ hs2, const float* __restrict__ b2,
    float* __restrict__ out, int n) {
  int t = blockIdx.x * blockDim.x + threadIdx.x;
  int d = t >> 3;
  if (d >= n) return;
  int ph = t & 7;

  float a[8] = {0.f, 0.f, 0.f, 0.f, 0.f, 0.f, 0.f, 0.f};
  if (ph == 0) acc8(a, hs2[d]);  // self loop (hs2 pre-scaled)

  int k = off[d] + ph, k1 = end[d];
  for (; k + 8 < k1; k += 16) {
    int s0 = srcs[k], s1 = srcs[k + 8];
    uint4 r0 = hs2[s0];
    uint4 r1 = hs2[s1];
    acc8(a, r0);
    acc8(a, r1);
  }
  if (k < k1) acc8(a, hs2[srcs[k]]);

#pragma unroll
  for (int i = 0; i < 8; ++i) {
    a[i] += __shfl_xor(a[i], 1);
    a[i] += __shfl_xor(a[i], 2);
    a[i] += __shfl_xor(a[i], 4);
  }
  float dd = dis[d];
  float u[NC];
#pragma unroll
  for (int c = 0; c < NC; ++c) u[c] = fmaxf(a[c] * dd + b2[c], 0.f);
  float m = u[0];
#pragma unroll
  for (int c = 1; c < NC; ++c) m = fmaxf(m, u[c]);
  float sum = 0.f;
#pragma unroll
  for (int c = 0; c < NC; ++c) sum += expf(u[c] - m);
  float lg = logf(sum);
  if (ph < NC) out[(size_t)d * NC + ph] = u[ph] - m - lg;
}

extern "C" void kernel_launch(void* const* d_in, const int* in_sizes, int n_in,
                              void* d_out, int out_size, void* d_ws, size_t ws_size,
                              hipStream_t stream) {
  const float* x  = (const float*)d_in[0];
  const int*   ei = (const int*)d_in[1];
  const float* W1 = (const float*)d_in[2];
  const float* b1 = (const float*)d_in[3];
  const float* W2 = (const float*)d_in[4];
  const float* b2 = (const float*)d_in[5];
  int n = in_sizes[0] / NF;   // 100000
  int E = in_sizes[1] / 2;    // 3200000
  int nbkt = (n + 127) >> 7;  // 782

  // workspace layout (each region 16B-aligned)
  char* w = (char*)d_ws;
#define TAKE(ptrty, name, bytes) \
  ptrty name = (ptrty)w; w += ((size_t)(bytes) + 15) & ~(size_t)15;
  TAKE(unsigned short*, hs1,  sizeof(short) * (size_t)n * NH)
  TAKE(uint4*,          hs2,  16 * (size_t)n)
  TAKE(float*,          dis,  sizeof(float) * n)
  TAKE(short*,          Wb,   sizeof(short) * NCH * 64 * 8)
  TAKE(int*,            bfill,sizeof(int) * 16 * NBKT_MAX)
  TAKE(int*,            ebuf, sizeof(int) * (size_t)NBKT_MAX * CAP)
  TAKE(int*,            off,  sizeof(int) * n)
  TAKE(int*,            end,  sizeof(int) * n)
  TAKE(int*,            srcs, sizeof(int) * (size_t)NBKT_MAX * CAP)
#undef TAKE
  float* out = (float*)d_out;

  int nsb = (E + SC_C - 1) / SC_C;  // 1042
  int ntb = (n + 15) / 16;          // 6250 gemm tiles

  // prep: pack W fragments + init fixed-cap bucket cursors
  k_prep<<<(NCH * 64 * 8 + 255) / 256, 256, 0, stream>>>(W1, Wb, bfill);

  // fused, role-interleaved: scatter iff blk%7==0 (1042 scatter + 6250 gemm)
  k_fused<<<nsb + ntb, 256, 0, stream>>>(x, Wb, ei, bfill, ebuf, hs1,
                                         n, E, nbkt, nsb);

  k_bcsr<<<nbkt, 512, 0, stream>>>(ebuf, bfill, off, end, srcs, dis, hs1, n);
  k_pull1<<<((size_t)n * 16 + 255) / 256, 256, 0, stream>>>(
      off, end, srcs, dis, (const uint4*)hs1, b1, W2, hs2, n);
  k_pull2<<<((size_t)n * 8 + 255) / 256, 256, 0, stream>>>(
      off, end, srcs, dis, hs2, b2, out, n);
}